// Round 1
// 302.432 us; speedup vs baseline: 1.1947x; 1.1947x over previous
//
#include <hip/hip_runtime.h>

#define N_NODES 100000
#define N_EDGES 1600000
constexpr int IN_F = 128, HID_F = 64, OUT_F = 16, N_CLS = 5;

// ---- dst-bucket partition parameters ----
constexpr int NPB = 128;                        // nodes per bucket (dst >> 7)
constexpr int NBK = (N_NODES + NPB - 1) / NPB;  // 782 buckets
constexpr int BCAP = 2400;                      // per-bucket capacity (mean 2048 + 7.8 sigma)
constexpr int FCH = 4096;                       // edges per fill chunk
constexpr int NCH = (N_EDGES + FCH - 1) / FCH;  // 391 chunks

typedef __attribute__((ext_vector_type(8))) short bf16x8;  // 4 VGPR A/B frag
typedef __attribute__((ext_vector_type(4))) float f32x4;   // 4 AGPR C/D frag

// bf16 helpers: values are finite floats.
__device__ __forceinline__ float bf_lo(unsigned u) {
  return __uint_as_float(u << 16);
}
__device__ __forceinline__ float bf_hi(unsigned u) {
  return __uint_as_float(u & 0xffff0000u);
}
__device__ __forceinline__ unsigned f2bf(float f) {  // RNE round to bf16
  unsigned u = __float_as_uint(f);
  return (u + 0x7fffu + ((u >> 16) & 1u)) >> 16;
}
// pack two exact-bf16 floats (low mantissa bits zero) into one dword
__device__ __forceinline__ unsigned packbf(float lo, float hi) {
  return (__float_as_uint(lo) >> 16) | (__float_as_uint(hi) & 0xffff0000u);
}
__device__ __forceinline__ void unpack8(uint4 u, float* f) {
  f[0] = bf_lo(u.x); f[1] = bf_hi(u.x);
  f[2] = bf_lo(u.y); f[3] = bf_hi(u.y);
  f[4] = bf_lo(u.z); f[5] = bf_hi(u.z);
  f[6] = bf_lo(u.w); f[7] = bf_hi(u.w);
}

// ---------------------------------------------------------------------------
// node_gemm_mfma: Y[n] = act( X1[n] @ W1 (+ X2[n] @ W2) + b ), bf16 MFMA.
// 4 waves/block, BM=64 (16 node-rows per wave). K tiled in KT=64 bf16.
// LDS: xt[64 rows][64 bf16] (128B rows, chunk XOR-swizzle c^=(row&7)) and
// wt[FOUT][64 bf16] (W transposed at stage so B-frags are 16B contiguous).
// Frags: A row=lane&15, k=(lane>>4)*8+j; B col=lane&15, same k.
// C/D: col=lane&15, row=(lane>>4)*4+reg [verified m89 mapping].
// ---------------------------------------------------------------------------
template <int K1, int FOUT, bool TWO, bool X1BF, bool X2BF, bool NORM,
          bool YBF>
__global__ __launch_bounds__(256) void node_gemm_mfma(
    const void* __restrict__ X1, const void* __restrict__ X2,
    const float* __restrict__ W1, const float* __restrict__ W2,
    const float* __restrict__ B, void* __restrict__ Y, int n) {
  constexpr int KT = 64;         // K-tile in bf16 elements
  constexpr int KT2 = KT / 2;    // 32 u32 per LDS row (128B, bank-aligned)
  constexpr int NT1 = K1 / KT;
  constexpr int NT = TWO ? 2 * NT1 : NT1;
  constexpr int NFT = FOUT / 16;  // n-tiles per wave
  constexpr int BM = 64;
  __shared__ unsigned xt[BM * KT2];
  __shared__ unsigned wt[FOUT * KT2];

  const int tid = threadIdx.x;
  const int base = blockIdx.x * BM;
  const int wave = tid >> 6, lane = tid & 63;
  const int l15 = lane & 15, l4 = lane >> 4;

  f32x4 acc[NFT];
#pragma unroll
  for (int nt = 0; nt < NFT; ++nt) {
    const float b = B[nt * 16 + l15];
    acc[nt] = {b, b, b, b};
  }

  for (int t = 0; t < NT; ++t) {
    const bool second = TWO && t >= NT1;
    const int kt0 = (t % NT1) * KT;
    // ---- stage X tile (packed bf16 u32, swizzled) ----
#pragma unroll
    for (int q = 0; q < BM * KT2 / 256; ++q) {
      const int idx = tid + q * 256;
      const int r = idx >> 5, c2 = idx & 31;
      const int node = base + r;
      unsigned pk = 0;
      if (node < n) {
        if (second) {
          if (X2BF) {
            pk = reinterpret_cast<const unsigned*>(
                X2)[(size_t)node * (K1 / 2) + kt0 / 2 + c2];
          } else {
            const float2 f2 = reinterpret_cast<const float2*>(
                X2)[(size_t)node * (K1 / 2) + kt0 / 2 + c2];
            pk = f2bf(f2.x) | (f2bf(f2.y) << 16);
          }
        } else {
          if (X1BF) {
            pk = reinterpret_cast<const unsigned*>(
                X1)[(size_t)node * (K1 / 2) + kt0 / 2 + c2];
          } else {
            const float2 f2 = reinterpret_cast<const float2*>(
                X1)[(size_t)node * (K1 / 2) + kt0 / 2 + c2];
            pk = f2bf(f2.x) | (f2bf(f2.y) << 16);
          }
        }
      }
      xt[r * KT2 + (c2 ^ ((r & 7) << 2))] = pk;
    }
    // ---- stage W tile transposed: wt[f][k] = W[kt0+k][f] ----
    {
      const float* __restrict__ Ws = second ? W2 : W1;
#pragma unroll
      for (int q = 0; q < FOUT * KT2 / 256; ++q) {
        const int idx = tid + q * 256;
        const int c2 = idx / FOUT, f = idx % FOUT;
        const float w0 = Ws[(size_t)(kt0 + 2 * c2) * FOUT + f];
        const float w1 = Ws[(size_t)(kt0 + 2 * c2 + 1) * FOUT + f];
        wt[f * KT2 + (c2 ^ ((f & 7) << 2))] = f2bf(w0) | (f2bf(w1) << 16);
      }
    }
    __syncthreads();
    // ---- MFMA: 2 k-steps of K=32 ----
#pragma unroll
    for (int ks = 0; ks < 2; ++ks) {
      const int ar = wave * 16 + l15;
      const bf16x8 af = *reinterpret_cast<const bf16x8*>(
          &xt[ar * KT2 + (((ks * 4 + l4) ^ (l15 & 7)) << 2)]);
#pragma unroll
      for (int nt = 0; nt < NFT; ++nt) {
        const int f = nt * 16 + l15;
        const bf16x8 bfr = *reinterpret_cast<const bf16x8*>(
            &wt[f * KT2 + (((ks * 4 + l4) ^ (l15 & 7)) << 2)]);
        acc[nt] =
            __builtin_amdgcn_mfma_f32_16x16x32_bf16(af, bfr, acc[nt], 0, 0, 0);
      }
    }
    __syncthreads();
  }

  // ---- epilogue: lane holds D[l4*4+reg][nt*16+l15] ----
  if (NORM) {
    float ss[4] = {0.f, 0.f, 0.f, 0.f};
#pragma unroll
    for (int nt = 0; nt < NFT; ++nt)
#pragma unroll
      for (int r = 0; r < 4; ++r) ss[r] += acc[nt][r] * acc[nt][r];
#pragma unroll
    for (int r = 0; r < 4; ++r) {
#pragma unroll
      for (int off = 1; off < 16; off <<= 1) ss[r] += __shfl_xor(ss[r], off, 16);
      ss[r] = 1.0f / fmaxf(sqrtf(ss[r]), 1e-12f);
    }
#pragma unroll
    for (int nt = 0; nt < NFT; ++nt)
#pragma unroll
      for (int r = 0; r < 4; ++r) acc[nt][r] = fmaxf(acc[nt][r] * ss[r], 0.f);
  } else {
#pragma unroll
    for (int nt = 0; nt < NFT; ++nt)
#pragma unroll
      for (int r = 0; r < 4; ++r) acc[nt][r] = fmaxf(acc[nt][r], 0.f);
  }
#pragma unroll
  for (int r = 0; r < 4; ++r) {
    const int node = base + wave * 16 + l4 * 4 + r;
    if (node < n) {
#pragma unroll
      for (int nt = 0; nt < NFT; ++nt) {
        if (YBF)
          reinterpret_cast<unsigned short*>(Y)[(size_t)node * FOUT + nt * 16 +
                                               l15] =
              (unsigned short)f2bf(acc[nt][r]);
        else
          reinterpret_cast<float*>(Y)[(size_t)node * FOUT + nt * 16 + l15] =
              acc[nt][r];
      }
    }
  }
}

// ---------------------------------------------------------------------------
// bucket_fill: single-pass radix partition of edges into NBK dst-buckets.
// Capacity layout (bucket b owns bedges[b*BCAP .. b*BCAP+BCAP)) removes the
// global scan. Per 4096-edge chunk: LDS histogram -> ONE cursor atomicAdd per
// nonzero bucket -> rank via LDS atomicAdd -> writes land rank-ordered, so a
// bucket's write window from this chunk is contiguous and line-local (fixes
// the 73MB->~8MB WRITE_SIZE thrash of csr_fill_part). Packed word:
// src (20 bits) | dst_local (7 bits) << 20.
// ---------------------------------------------------------------------------
__global__ __launch_bounds__(256) void bucket_fill(
    const int* __restrict__ src, const int* __restrict__ dst,
    int* __restrict__ cursor, unsigned* __restrict__ bedges) {
  __shared__ int hist[NBK];
  __shared__ int bbase[NBK];
  const int tid = threadIdx.x;
  const int c0 = blockIdx.x * FCH;
  const int n4 = (min(FCH, N_EDGES - c0)) >> 2;  // int4 count in this chunk
  for (int i = tid; i < NBK; i += 256) hist[i] = 0;
  __syncthreads();
  const int4* __restrict__ s4 = reinterpret_cast<const int4*>(src + c0);
  const int4* __restrict__ d4 = reinterpret_cast<const int4*>(dst + c0);
  int4 sv[4], dv[4];
#pragma unroll
  for (int q = 0; q < 4; ++q) {
    const int i = tid + q * 256;
    if (i < n4) {
      sv[q] = s4[i];
      dv[q] = d4[i];
      atomicAdd(&hist[dv[q].x >> 7], 1);
      atomicAdd(&hist[dv[q].y >> 7], 1);
      atomicAdd(&hist[dv[q].z >> 7], 1);
      atomicAdd(&hist[dv[q].w >> 7], 1);
    }
  }
  __syncthreads();
  for (int i = tid; i < NBK; i += 256) {
    const int c = hist[i];
    bbase[i] = c ? atomicAdd(&cursor[i], c) : 0;
    hist[i] = 0;  // reuse as rank counter
  }
  __syncthreads();
#pragma unroll
  for (int q = 0; q < 4; ++q) {
    const int i = tid + q * 256;
    if (i < n4) {
#define PUT(dd, ss)                                        \
  {                                                        \
    const int b_ = (dd) >> 7;                              \
    const int r_ = bbase[b_] + atomicAdd(&hist[b_], 1);    \
    if (r_ < BCAP)                                         \
      bedges[(size_t)b_ * BCAP + r_] =                     \
          (unsigned)(ss) | ((unsigned)((dd) & 127) << 20); \
  }
      PUT(dv[q].x, sv[q].x)
      PUT(dv[q].y, sv[q].y)
      PUT(dv[q].z, sv[q].z)
      PUT(dv[q].w, sv[q].w)
#undef PUT
    }
  }
}

// ---------------------------------------------------------------------------
// scatter_max<NSLICE>: fused CSR-fill + gather replacement. One block per
// (bucket, 64-feature slice). LDS accumulator float[128][68] (stride 68
// breaks the stride-64 bank aliasing across 8-lane edge groups). Max done
// directly on bf16 bits shifted into f32 bit position via atomicMax(u32) --
// valid since m = relu(...) >= 0 makes IEEE bits monotone as unsigned.
// LDS 0-init == reference's where(isneginf, 0). 8 lanes per edge (uint4 =
// 8 bf16 each), 8 edges per wave-iteration, 8 ds_max_u32 per iteration.
// LDS = 128*68*4 = 34.8KB -> 4 blocks/CU, 16 waves/CU for latency hiding.
// ---------------------------------------------------------------------------
template <int NSLICE>
__global__ __launch_bounds__(256, 4) void scatter_max(
    const uint4* __restrict__ M4, const unsigned* __restrict__ bedges,
    const int* __restrict__ cnt, uint4* __restrict__ A4) {
  __shared__ unsigned aggl[NPB * 68];
  const int b = blockIdx.x / NSLICE;
  const int slice = blockIdx.x % NSLICE;
  for (int i = threadIdx.x; i < NPB * 68; i += 256) aggl[i] = 0;
  __syncthreads();
  const int wave = threadIdx.x >> 6, lane = threadIdx.x & 63;
  const int g = lane >> 3, sl = lane & 7;
  const int beg = b * BCAP;
  const int end = beg + min(cnt[b], BCAP);
  for (int ebase = beg + wave * 8; ebase < end; ebase += 32) {
    const int e = ebase + g;
    if (e < end) {
      const unsigned wv = bedges[e];
      const int srcn = wv & 0xFFFFF;
      const int dl = wv >> 20;
      const uint4 r = M4[(size_t)srcn * (NSLICE * 8) + slice * 8 + sl];
      unsigned* a = &aggl[dl * 68 + sl * 8];
      atomicMax(&a[0], r.x << 16);
      atomicMax(&a[1], r.x & 0xffff0000u);
      atomicMax(&a[2], r.y << 16);
      atomicMax(&a[3], r.y & 0xffff0000u);
      atomicMax(&a[4], r.z << 16);
      atomicMax(&a[5], r.z & 0xffff0000u);
      atomicMax(&a[6], r.w << 16);
      atomicMax(&a[7], r.w & 0xffff0000u);
    }
  }
  __syncthreads();
  const int node0 = b * NPB;
  for (int nb = wave * 8 + g; nb < NPB; nb += 32) {
    const int node = node0 + nb;
    if (node < N_NODES) {
      const unsigned* s = &aggl[nb * 68 + sl * 8];
      uint4 o;
      o.x = (s[0] >> 16) | (s[1] & 0xffff0000u);
      o.y = (s[2] >> 16) | (s[3] & 0xffff0000u);
      o.z = (s[4] >> 16) | (s[5] & 0xffff0000u);
      o.w = (s[6] >> 16) | (s[7] & 0xffff0000u);
      A4[(size_t)node * (NSLICE * 8) + slice * 8 + sl] = o;
    }
  }
}

// ---------------------------------------------------------------------------
// Edge scoring, bf16 h rows (16 bf16 = 2x uint4 per row).
// ---------------------------------------------------------------------------
__global__ __launch_bounds__(256) void edge_score_bf16_kernel(
    const uint4* __restrict__ H, const int* __restrict__ src,
    const int* __restrict__ dst, const float* __restrict__ PW,
    const float* __restrict__ PB, float* __restrict__ OUT) {
  __shared__ float Wl[2 * OUT_F * N_CLS];
  __shared__ float bl[N_CLS];
  if (threadIdx.x < 2 * OUT_F * N_CLS) Wl[threadIdx.x] = PW[threadIdx.x];
  if (threadIdx.x < N_CLS) bl[threadIdx.x] = PB[threadIdx.x];
  __syncthreads();
  for (int e = blockIdx.x * 256 + threadIdx.x; e < N_EDGES;
       e += gridDim.x * 256) {
    const int s = src[e], d = dst[e];
    const uint4 s0 = H[(size_t)s * 2], s1 = H[(size_t)s * 2 + 1];
    const uint4 d0 = H[(size_t)d * 2], d1 = H[(size_t)d * 2 + 1];
    float hs[OUT_F], hd[OUT_F];
    unpack8(s0, hs); unpack8(s1, hs + 8);
    unpack8(d0, hd); unpack8(d1, hd + 8);
    float acc[N_CLS];
#pragma unroll
    for (int c = 0; c < N_CLS; ++c) acc[c] = bl[c];
#pragma unroll
    for (int k = 0; k < OUT_F; ++k) {
#pragma unroll
      for (int c = 0; c < N_CLS; ++c) {
        acc[c] = fmaf(hs[k], Wl[k * N_CLS + c], acc[c]);
        acc[c] = fmaf(hd[k], Wl[(OUT_F + k) * N_CLS + c], acc[c]);
      }
    }
    float* o = OUT + (size_t)e * N_CLS;
#pragma unroll
    for (int c = 0; c < N_CLS; ++c) o[c] = acc[c];
  }
}

extern "C" void kernel_launch(void* const* d_in, const int* in_sizes, int n_in,
                              void* d_out, int out_size, void* d_ws,
                              size_t ws_size, hipStream_t stream) {
  const float* x = (const float*)d_in[0];
  const int* src = (const int*)d_in[1];
  const int* dst = (const int*)d_in[2];
  const float* pool1_W = (const float*)d_in[3];
  const float* pool1_b = (const float*)d_in[4];
  const float* self1_W = (const float*)d_in[5];
  const float* neigh1_W = (const float*)d_in[6];
  const float* bias1 = (const float*)d_in[7];
  const float* pool2_W = (const float*)d_in[8];
  const float* pool2_b = (const float*)d_in[9];
  const float* self2_W = (const float*)d_in[10];
  const float* neigh2_W = (const float*)d_in[11];
  const float* bias2 = (const float*)d_in[12];
  const float* pred_W = (const float*)d_in[13];
  const float* pred_b = (const float*)d_in[14];
  float* out = (float*)d_out;

  // Workspace: cursor (1024 ints) + bedges (NBK*BCAP u32 ~= 7.5MB, less than
  // the old CSR int region), then the same two 25.6MB bf16 regions.
  int* cursor = (int*)d_ws;                        // 1024 (uses NBK=782)
  unsigned* bedges = (unsigned*)(cursor + 1024);   // 782*2400 = 1,876,800
  char* bufA = (char*)(bedges + (size_t)NBK * BCAP);  // 25.6MB
  char* bufB = bufA + 25600000;                       // 25.6MB
  void* m1 = (void*)bufA;                 // bf16 [N,128] (25.6MB)
  void* agg1 = (void*)bufB;               // bf16 [N,128]
  void* h1 = (void*)bufA;                 // bf16 [N,64] 12.8MB (m1 dead)
  void* m2 = (void*)bufB;                 // bf16 [N,64] (agg1 dead)
  void* agg2 = (void*)(bufA + 12800000);  // bf16 [N,64] (m1 upper half, dead)
  void* h2 = (void*)bufB;                 // bf16 [N,16] (m2 dead after scatter2)

  // ---- edge bucketing (replaces hist/scan/csr_fill) ----
  hipMemsetAsync(cursor, 0, 1024 * sizeof(int), stream);
  bucket_fill<<<NCH, 256, 0, stream>>>(src, dst, cursor, bedges);

  const int ngrid = (N_NODES + 63) / 64;  // 1563

  // ---- Layer 1 ----
  node_gemm_mfma<IN_F, IN_F, false, false, false, false, true>
      <<<ngrid, 256, 0, stream>>>(x, nullptr, pool1_W, nullptr, pool1_b, m1,
                                  N_NODES);
  scatter_max<2><<<NBK * 2, 256, 0, stream>>>((const uint4*)m1, bedges, cursor,
                                              (uint4*)agg1);
  node_gemm_mfma<IN_F, HID_F, true, false, true, true, true>
      <<<ngrid, 256, 0, stream>>>(x, agg1, self1_W, neigh1_W, bias1, h1,
                                  N_NODES);

  // ---- Layer 2 ----
  node_gemm_mfma<HID_F, HID_F, false, true, false, false, true>
      <<<ngrid, 256, 0, stream>>>(h1, nullptr, pool2_W, nullptr, pool2_b, m2,
                                  N_NODES);
  scatter_max<1><<<NBK, 256, 0, stream>>>((const uint4*)m2, bedges, cursor,
                                          (uint4*)agg2);
  node_gemm_mfma<HID_F, OUT_F, true, true, true, true, true>
      <<<ngrid, 256, 0, stream>>>(h1, agg2, self2_W, neigh2_W, bias2, h2,
                                  N_NODES);

  // ---- Edge scoring ----
  edge_score_bf16_kernel<<<4096, 256, 0, stream>>>((const uint4*)h2, src, dst,
                                                   pred_W, pred_b, out);
}

// Round 2
// 239.786 us; speedup vs baseline: 1.5068x; 1.2613x over previous
//
#include <hip/hip_runtime.h>

#define N_NODES 100000
#define N_EDGES 1600000
constexpr int IN_F = 128, HID_F = 64, OUT_F = 16, N_CLS = 5;

// ---- dst-bucket partition parameters ----
constexpr int NPB = 128;                        // nodes per bucket (dst >> 7)
constexpr int NBK = (N_NODES + NPB - 1) / NPB;  // 782 buckets
constexpr int BCAP = 2400;                      // per-bucket capacity (mean 2048 + 7.8 sigma)
constexpr int FCH = 4096;                       // edges per fill chunk
constexpr int NCH = (N_EDGES + FCH - 1) / FCH;  // 391 chunks

typedef __attribute__((ext_vector_type(8))) short bf16x8;  // 4 VGPR A/B frag
typedef __attribute__((ext_vector_type(4))) float f32x4;   // 4 AGPR C/D frag
typedef __attribute__((ext_vector_type(2))) unsigned short u16x2;

// bf16 helpers: values are finite floats.
__device__ __forceinline__ float bf_lo(unsigned u) {
  return __uint_as_float(u << 16);
}
__device__ __forceinline__ float bf_hi(unsigned u) {
  return __uint_as_float(u & 0xffff0000u);
}
__device__ __forceinline__ unsigned f2bf(float f) {  // RNE round to bf16
  unsigned u = __float_as_uint(f);
  return (u + 0x7fffu + ((u >> 16) & 1u)) >> 16;
}
__device__ __forceinline__ void unpack8(uint4 u, float* f) {
  f[0] = bf_lo(u.x); f[1] = bf_hi(u.x);
  f[2] = bf_lo(u.y); f[3] = bf_hi(u.y);
  f[4] = bf_lo(u.z); f[5] = bf_hi(u.z);
  f[6] = bf_lo(u.w); f[7] = bf_hi(u.w);
}

// Packed max of two bf16 lanes as u16 pairs -- exact for post-ReLU (>=0)
// bf16 values since IEEE bits are monotone as unsigned there. Selects
// v_pk_max_u16 (single VALU op), no unpack/repack needed.
__device__ __forceinline__ unsigned pkmax(unsigned a, unsigned b) {
  const u16x2 r = __builtin_elementwise_max(__builtin_bit_cast(u16x2, a),
                                            __builtin_bit_cast(u16x2, b));
  return __builtin_bit_cast(unsigned, r);
}
__device__ __forceinline__ uint4 pkmax4(uint4 a, uint4 b) {
  a.x = pkmax(a.x, b.x);
  a.y = pkmax(a.y, b.y);
  a.z = pkmax(a.z, b.z);
  a.w = pkmax(a.w, b.w);
  return a;
}

// ---------------------------------------------------------------------------
// node_gemm_mfma: Y[n] = act( X1[n] @ W1 (+ X2[n] @ W2) + b ), bf16 MFMA.
// 4 waves/block, BM=64 (16 node-rows per wave). K tiled in KT=64 bf16.
// LDS: xt[64 rows][64 bf16] (128B rows, chunk XOR-swizzle c^=(row&7)) and
// wt[FOUT][64 bf16] (W transposed at stage so B-frags are 16B contiguous).
// Frags: A row=lane&15, k=(lane>>4)*8+j; B col=lane&15, same k.
// C/D: col=lane&15, row=(lane>>4)*4+reg [verified m89 mapping].
// ---------------------------------------------------------------------------
template <int K1, int FOUT, bool TWO, bool X1BF, bool X2BF, bool NORM,
          bool YBF>
__global__ __launch_bounds__(256) void node_gemm_mfma(
    const void* __restrict__ X1, const void* __restrict__ X2,
    const float* __restrict__ W1, const float* __restrict__ W2,
    const float* __restrict__ B, void* __restrict__ Y, int n) {
  constexpr int KT = 64;         // K-tile in bf16 elements
  constexpr int KT2 = KT / 2;    // 32 u32 per LDS row (128B, bank-aligned)
  constexpr int NT1 = K1 / KT;
  constexpr int NT = TWO ? 2 * NT1 : NT1;
  constexpr int NFT = FOUT / 16;  // n-tiles per wave
  constexpr int BM = 64;
  __shared__ unsigned xt[BM * KT2];
  __shared__ unsigned wt[FOUT * KT2];

  const int tid = threadIdx.x;
  const int base = blockIdx.x * BM;
  const int wave = tid >> 6, lane = tid & 63;
  const int l15 = lane & 15, l4 = lane >> 4;

  f32x4 acc[NFT];
#pragma unroll
  for (int nt = 0; nt < NFT; ++nt) {
    const float b = B[nt * 16 + l15];
    acc[nt] = {b, b, b, b};
  }

  for (int t = 0; t < NT; ++t) {
    const bool second = TWO && t >= NT1;
    const int kt0 = (t % NT1) * KT;
    // ---- stage X tile (packed bf16 u32, swizzled) ----
#pragma unroll
    for (int q = 0; q < BM * KT2 / 256; ++q) {
      const int idx = tid + q * 256;
      const int r = idx >> 5, c2 = idx & 31;
      const int node = base + r;
      unsigned pk = 0;
      if (node < n) {
        if (second) {
          if (X2BF) {
            pk = reinterpret_cast<const unsigned*>(
                X2)[(size_t)node * (K1 / 2) + kt0 / 2 + c2];
          } else {
            const float2 f2 = reinterpret_cast<const float2*>(
                X2)[(size_t)node * (K1 / 2) + kt0 / 2 + c2];
            pk = f2bf(f2.x) | (f2bf(f2.y) << 16);
          }
        } else {
          if (X1BF) {
            pk = reinterpret_cast<const unsigned*>(
                X1)[(size_t)node * (K1 / 2) + kt0 / 2 + c2];
          } else {
            const float2 f2 = reinterpret_cast<const float2*>(
                X1)[(size_t)node * (K1 / 2) + kt0 / 2 + c2];
            pk = f2bf(f2.x) | (f2bf(f2.y) << 16);
          }
        }
      }
      xt[r * KT2 + (c2 ^ ((r & 7) << 2))] = pk;
    }
    // ---- stage W tile transposed: wt[f][k] = W[kt0+k][f] ----
    {
      const float* __restrict__ Ws = second ? W2 : W1;
#pragma unroll
      for (int q = 0; q < FOUT * KT2 / 256; ++q) {
        const int idx = tid + q * 256;
        const int c2 = idx / FOUT, f = idx % FOUT;
        const float w0 = Ws[(size_t)(kt0 + 2 * c2) * FOUT + f];
        const float w1 = Ws[(size_t)(kt0 + 2 * c2 + 1) * FOUT + f];
        wt[f * KT2 + (c2 ^ ((f & 7) << 2))] = f2bf(w0) | (f2bf(w1) << 16);
      }
    }
    __syncthreads();
    // ---- MFMA: 2 k-steps of K=32 ----
#pragma unroll
    for (int ks = 0; ks < 2; ++ks) {
      const int ar = wave * 16 + l15;
      const bf16x8 af = *reinterpret_cast<const bf16x8*>(
          &xt[ar * KT2 + (((ks * 4 + l4) ^ (l15 & 7)) << 2)]);
#pragma unroll
      for (int nt = 0; nt < NFT; ++nt) {
        const int f = nt * 16 + l15;
        const bf16x8 bfr = *reinterpret_cast<const bf16x8*>(
            &wt[f * KT2 + (((ks * 4 + l4) ^ (l15 & 7)) << 2)]);
        acc[nt] =
            __builtin_amdgcn_mfma_f32_16x16x32_bf16(af, bfr, acc[nt], 0, 0, 0);
      }
    }
    __syncthreads();
  }

  // ---- epilogue: lane holds D[l4*4+reg][nt*16+l15] ----
  if (NORM) {
    float ss[4] = {0.f, 0.f, 0.f, 0.f};
#pragma unroll
    for (int nt = 0; nt < NFT; ++nt)
#pragma unroll
      for (int r = 0; r < 4; ++r) ss[r] += acc[nt][r] * acc[nt][r];
#pragma unroll
    for (int r = 0; r < 4; ++r) {
#pragma unroll
      for (int off = 1; off < 16; off <<= 1) ss[r] += __shfl_xor(ss[r], off, 16);
      ss[r] = 1.0f / fmaxf(sqrtf(ss[r]), 1e-12f);
    }
#pragma unroll
    for (int nt = 0; nt < NFT; ++nt)
#pragma unroll
      for (int r = 0; r < 4; ++r) acc[nt][r] = fmaxf(acc[nt][r] * ss[r], 0.f);
  } else {
#pragma unroll
    for (int nt = 0; nt < NFT; ++nt)
#pragma unroll
      for (int r = 0; r < 4; ++r) acc[nt][r] = fmaxf(acc[nt][r], 0.f);
  }
#pragma unroll
  for (int r = 0; r < 4; ++r) {
    const int node = base + wave * 16 + l4 * 4 + r;
    if (node < n) {
#pragma unroll
      for (int nt = 0; nt < NFT; ++nt) {
        if (YBF)
          reinterpret_cast<unsigned short*>(Y)[(size_t)node * FOUT + nt * 16 +
                                               l15] =
              (unsigned short)f2bf(acc[nt][r]);
        else
          reinterpret_cast<float*>(Y)[(size_t)node * FOUT + nt * 16 + l15] =
              acc[nt][r];
      }
    }
  }
}

// ---------------------------------------------------------------------------
// bucket_fill: single-pass radix partition of edges into NBK dst-buckets.
// Capacity layout (bucket b owns bedges[b*BCAP .. b*BCAP+BCAP)) removes the
// global scan. Per 4096-edge chunk: LDS histogram -> ONE cursor atomicAdd per
// nonzero bucket -> rank via LDS atomicAdd -> clustered line-local writes.
// Packed word: src (20 bits) | dst_local (7 bits) << 20.
// ---------------------------------------------------------------------------
__global__ __launch_bounds__(256) void bucket_fill(
    const int* __restrict__ src, const int* __restrict__ dst,
    int* __restrict__ cursor, unsigned* __restrict__ bedges) {
  __shared__ int hist[NBK];
  __shared__ int bbase[NBK];
  const int tid = threadIdx.x;
  const int c0 = blockIdx.x * FCH;
  const int n4 = (min(FCH, N_EDGES - c0)) >> 2;  // int4 count in this chunk
  for (int i = tid; i < NBK; i += 256) hist[i] = 0;
  __syncthreads();
  const int4* __restrict__ s4 = reinterpret_cast<const int4*>(src + c0);
  const int4* __restrict__ d4 = reinterpret_cast<const int4*>(dst + c0);
  int4 sv[4], dv[4];
#pragma unroll
  for (int q = 0; q < 4; ++q) {
    const int i = tid + q * 256;
    if (i < n4) {
      sv[q] = s4[i];
      dv[q] = d4[i];
      atomicAdd(&hist[dv[q].x >> 7], 1);
      atomicAdd(&hist[dv[q].y >> 7], 1);
      atomicAdd(&hist[dv[q].z >> 7], 1);
      atomicAdd(&hist[dv[q].w >> 7], 1);
    }
  }
  __syncthreads();
  for (int i = tid; i < NBK; i += 256) {
    const int c = hist[i];
    bbase[i] = c ? atomicAdd(&cursor[i], c) : 0;
    hist[i] = 0;  // reuse as rank counter
  }
  __syncthreads();
#pragma unroll
  for (int q = 0; q < 4; ++q) {
    const int i = tid + q * 256;
    if (i < n4) {
#define PUT(dd, ss)                                        \
  {                                                        \
    const int b_ = (dd) >> 7;                              \
    const int r_ = bbase[b_] + atomicAdd(&hist[b_], 1);    \
    if (r_ < BCAP)                                         \
      bedges[(size_t)b_ * BCAP + r_] =                     \
          (unsigned)(ss) | ((unsigned)((dd) & 127) << 20); \
  }
      PUT(dv[q].x, sv[q].x)
      PUT(dv[q].y, sv[q].y)
      PUT(dv[q].z, sv[q].z)
      PUT(dv[q].w, sv[q].w)
#undef PUT
    }
  }
}

// ---------------------------------------------------------------------------
// bucket_sort: one block per bucket. Counting-sort the bucket's edges by
// dst_local entirely in LDS (histogram -> Hillis-Steele scan -> rank
// scatter -> coalesced write-back in place, now storing plain src ids).
// Emits ninfo[node] = beg_local | (count << 12) (both < 4096). This gives
// the gather a per-node contiguous run with zero global scan.
// ---------------------------------------------------------------------------
__global__ __launch_bounds__(256) void bucket_sort(unsigned* __restrict__ bedges,
                                                   const int* __restrict__ cnt,
                                                   int* __restrict__ ninfo) {
  __shared__ unsigned el[BCAP];
  __shared__ unsigned el2[BCAP];
  __shared__ int hist[NPB];
  __shared__ int csum[NPB];
  __shared__ int posl[NPB];
  const int b = blockIdx.x;
  const int n = min(cnt[b], BCAP);
  unsigned* __restrict__ bp = bedges + (size_t)b * BCAP;
  for (int i = threadIdx.x; i < n; i += 256) el[i] = bp[i];
  for (int i = threadIdx.x; i < NPB; i += 256) hist[i] = 0;
  __syncthreads();
  for (int i = threadIdx.x; i < n; i += 256) atomicAdd(&hist[el[i] >> 20], 1);
  __syncthreads();
  if (threadIdx.x < NPB) csum[threadIdx.x] = hist[threadIdx.x];
  __syncthreads();
  for (int off = 1; off < NPB; off <<= 1) {
    int u = 0;
    if (threadIdx.x < NPB && threadIdx.x >= off) u = csum[threadIdx.x - off];
    __syncthreads();
    if (threadIdx.x < NPB) csum[threadIdx.x] += u;
    __syncthreads();
  }
  if (threadIdx.x < NPB) {
    const int c = hist[threadIdx.x];
    const int beg = csum[threadIdx.x] - c;  // exclusive prefix
    posl[threadIdx.x] = beg;
    const int node = b * NPB + threadIdx.x;
    if (node < N_NODES) ninfo[node] = beg | (c << 12);
  }
  __syncthreads();
  for (int i = threadIdx.x; i < n; i += 256) {
    const unsigned w = el[i];
    const int p = atomicAdd(&posl[w >> 20], 1);
    el2[p] = w & 0xFFFFF;
  }
  __syncthreads();
  for (int i = threadIdx.x; i < n; i += 256) bp[i] = el2[i];
}

// ---------------------------------------------------------------------------
// gather_max_pk<LPN>: per-node segment-max over sorted bucket runs.
// LPN lanes per node, uint4 = 8 bf16/lane. No LDS, no atomics; packed
// v_pk_max_u16 folds (exact for post-ReLU bf16). Zero-init == reference's
// where(isneginf, 0) for empty segments.
// ---------------------------------------------------------------------------
template <int LPN>
__global__ __launch_bounds__(256) void gather_max_pk(
    const uint4* __restrict__ M4, const int* __restrict__ ninfo,
    const int* __restrict__ sedges, uint4* __restrict__ A4) {
  constexpr int GPB = 256 / LPN;
  const int li = threadIdx.x % LPN;
  const int g0 = blockIdx.x * GPB + threadIdx.x / LPN;
  const int stride = gridDim.x * GPB;
  for (int node = g0; node < N_NODES; node += stride) {
    const int w = ninfo[node];
    const int beg = (node >> 7) * BCAP + (w & 0xFFF);
    const int end = beg + (w >> 12);
    uint4 a = {0u, 0u, 0u, 0u};
    int j = beg;
    for (; j + 3 < end; j += 4) {
      const int s0 = sedges[j], s1 = sedges[j + 1];
      const int s2 = sedges[j + 2], s3 = sedges[j + 3];
      const uint4 u0 = M4[(size_t)s0 * LPN + li];
      const uint4 u1 = M4[(size_t)s1 * LPN + li];
      const uint4 u2 = M4[(size_t)s2 * LPN + li];
      const uint4 u3 = M4[(size_t)s3 * LPN + li];
      a = pkmax4(a, u0);
      a = pkmax4(a, u1);
      a = pkmax4(a, u2);
      a = pkmax4(a, u3);
    }
    for (; j < end; ++j) a = pkmax4(a, M4[(size_t)sedges[j] * LPN + li]);
    A4[(size_t)node * LPN + li] = a;
  }
}

// ---------------------------------------------------------------------------
// Edge scoring, bf16 h rows (16 bf16 = 2x uint4 per row).
// ---------------------------------------------------------------------------
__global__ __launch_bounds__(256) void edge_score_bf16_kernel(
    const uint4* __restrict__ H, const int* __restrict__ src,
    const int* __restrict__ dst, const float* __restrict__ PW,
    const float* __restrict__ PB, float* __restrict__ OUT) {
  __shared__ float Wl[2 * OUT_F * N_CLS];
  __shared__ float bl[N_CLS];
  if (threadIdx.x < 2 * OUT_F * N_CLS) Wl[threadIdx.x] = PW[threadIdx.x];
  if (threadIdx.x < N_CLS) bl[threadIdx.x] = PB[threadIdx.x];
  __syncthreads();
  for (int e = blockIdx.x * 256 + threadIdx.x; e < N_EDGES;
       e += gridDim.x * 256) {
    const int s = src[e], d = dst[e];
    const uint4 s0 = H[(size_t)s * 2], s1 = H[(size_t)s * 2 + 1];
    const uint4 d0 = H[(size_t)d * 2], d1 = H[(size_t)d * 2 + 1];
    float hs[OUT_F], hd[OUT_F];
    unpack8(s0, hs); unpack8(s1, hs + 8);
    unpack8(d0, hd); unpack8(d1, hd + 8);
    float acc[N_CLS];
#pragma unroll
    for (int c = 0; c < N_CLS; ++c) acc[c] = bl[c];
#pragma unroll
    for (int k = 0; k < OUT_F; ++k) {
#pragma unroll
      for (int c = 0; c < N_CLS; ++c) {
        acc[c] = fmaf(hs[k], Wl[k * N_CLS + c], acc[c]);
        acc[c] = fmaf(hd[k], Wl[(OUT_F + k) * N_CLS + c], acc[c]);
      }
    }
    float* o = OUT + (size_t)e * N_CLS;
#pragma unroll
    for (int c = 0; c < N_CLS; ++c) o[c] = acc[c];
  }
}

extern "C" void kernel_launch(void* const* d_in, const int* in_sizes, int n_in,
                              void* d_out, int out_size, void* d_ws,
                              size_t ws_size, hipStream_t stream) {
  const float* x = (const float*)d_in[0];
  const int* src = (const int*)d_in[1];
  const int* dst = (const int*)d_in[2];
  const float* pool1_W = (const float*)d_in[3];
  const float* pool1_b = (const float*)d_in[4];
  const float* self1_W = (const float*)d_in[5];
  const float* neigh1_W = (const float*)d_in[6];
  const float* bias1 = (const float*)d_in[7];
  const float* pool2_W = (const float*)d_in[8];
  const float* pool2_b = (const float*)d_in[9];
  const float* self2_W = (const float*)d_in[10];
  const float* neigh2_W = (const float*)d_in[11];
  const float* bias2 = (const float*)d_in[12];
  const float* pred_W = (const float*)d_in[13];
  const float* pred_b = (const float*)d_in[14];
  float* out = (float*)d_out;

  // Workspace: cursor (1024) + ninfo (100352) + bedges (NBK*BCAP ~7.5MB)
  // + two 25.6MB bf16 regions. ~59.1MB total.
  int* cursor = (int*)d_ws;                      // 1024 (uses NBK=782)
  int* ninfo = cursor + 1024;                    // 100352 (uses 100000)
  unsigned* bedges = (unsigned*)(ninfo + 100352);  // 782*2400 = 1,876,800
  char* bufA = (char*)(bedges + (size_t)NBK * BCAP);  // 25.6MB
  char* bufB = bufA + 25600000;                       // 25.6MB
  void* m1 = (void*)bufA;                 // bf16 [N,128] (25.6MB)
  void* agg1 = (void*)bufB;               // bf16 [N,128]
  void* h1 = (void*)bufA;                 // bf16 [N,64] 12.8MB (m1 dead)
  void* m2 = (void*)bufB;                 // bf16 [N,64] (agg1 dead)
  void* agg2 = (void*)(bufA + 12800000);  // bf16 [N,64] (m1 upper half, dead)
  void* h2 = (void*)bufB;                 // bf16 [N,16] (m2 dead after gather2)

  // ---- edge bucketing + bucket-local counting sort ----
  hipMemsetAsync(cursor, 0, 1024 * sizeof(int), stream);
  bucket_fill<<<NCH, 256, 0, stream>>>(src, dst, cursor, bedges);
  bucket_sort<<<NBK, 256, 0, stream>>>(bedges, cursor, ninfo);

  const int ngrid = (N_NODES + 63) / 64;  // 1563

  // ---- Layer 1 ----
  node_gemm_mfma<IN_F, IN_F, false, false, false, false, true>
      <<<ngrid, 256, 0, stream>>>(x, nullptr, pool1_W, nullptr, pool1_b, m1,
                                  N_NODES);
  gather_max_pk<16><<<2048, 256, 0, stream>>>(
      (const uint4*)m1, ninfo, (const int*)bedges, (uint4*)agg1);
  node_gemm_mfma<IN_F, HID_F, true, false, true, true, true>
      <<<ngrid, 256, 0, stream>>>(x, agg1, self1_W, neigh1_W, bias1, h1,
                                  N_NODES);

  // ---- Layer 2 ----
  node_gemm_mfma<HID_F, HID_F, false, true, false, false, true>
      <<<ngrid, 256, 0, stream>>>(h1, nullptr, pool2_W, nullptr, pool2_b, m2,
                                  N_NODES);
  gather_max_pk<8><<<2048, 256, 0, stream>>>(
      (const uint4*)m2, ninfo, (const int*)bedges, (uint4*)agg2);
  node_gemm_mfma<HID_F, OUT_F, true, true, true, true, true>
      <<<ngrid, 256, 0, stream>>>(h1, agg2, self2_W, neigh2_W, bias2, h2,
                                  N_NODES);

  // ---- Edge scoring ----
  edge_score_bf16_kernel<<<4096, 256, 0, stream>>>((const uint4*)h2, src, dst,
                                                   pred_W, pred_b, out);
}

// Round 3
// 238.873 us; speedup vs baseline: 1.5125x; 1.0038x over previous
//
#include <hip/hip_runtime.h>

#define N_NODES 100000
#define N_EDGES 1600000
constexpr int IN_F = 128, HID_F = 64, OUT_F = 16, N_CLS = 5;

// ---- dst-bucket partition parameters ----
constexpr int NPB = 128;                        // nodes per bucket (dst >> 7)
constexpr int NBK = (N_NODES + NPB - 1) / NPB;  // 782 buckets
constexpr int BCAP = 2400;                      // per-bucket capacity (mean 2048 + 7.8 sigma)
constexpr int FCH = 4096;                       // edges per fill chunk
constexpr int NCH = (N_EDGES + FCH - 1) / FCH;  // 391 chunks

typedef __attribute__((ext_vector_type(8))) short bf16x8;  // 4 VGPR A/B frag
typedef __attribute__((ext_vector_type(4))) float f32x4;   // 4 AGPR C/D frag
typedef __attribute__((ext_vector_type(2))) unsigned short u16x2;

// bf16 helpers: values are finite floats.
__device__ __forceinline__ float bf_lo(unsigned u) {
  return __uint_as_float(u << 16);
}
__device__ __forceinline__ float bf_hi(unsigned u) {
  return __uint_as_float(u & 0xffff0000u);
}
__device__ __forceinline__ unsigned f2bf(float f) {  // RNE round to bf16
  unsigned u = __float_as_uint(f);
  return (u + 0x7fffu + ((u >> 16) & 1u)) >> 16;
}
__device__ __forceinline__ void unpack8(uint4 u, float* f) {
  f[0] = bf_lo(u.x); f[1] = bf_hi(u.x);
  f[2] = bf_lo(u.y); f[3] = bf_hi(u.y);
  f[4] = bf_lo(u.z); f[5] = bf_hi(u.z);
  f[6] = bf_lo(u.w); f[7] = bf_hi(u.w);
}

// Packed max of two bf16 lanes as u16 pairs -- exact for post-ReLU (>=0)
// bf16 values since IEEE bits are monotone as unsigned there. Selects
// v_pk_max_u16 (single VALU op), no unpack/repack needed.
__device__ __forceinline__ unsigned pkmax(unsigned a, unsigned b) {
  const u16x2 r = __builtin_elementwise_max(__builtin_bit_cast(u16x2, a),
                                            __builtin_bit_cast(u16x2, b));
  return __builtin_bit_cast(unsigned, r);
}
__device__ __forceinline__ uint4 pkmax4(uint4 a, uint4 b) {
  a.x = pkmax(a.x, b.x);
  a.y = pkmax(a.y, b.y);
  a.z = pkmax(a.z, b.z);
  a.w = pkmax(a.w, b.w);
  return a;
}

// ---------------------------------------------------------------------------
// node_gemm_mfma: Y[n] = act( X1[n] @ W1 (+ X2[n] @ W2) + b ), bf16 MFMA.
// 4 waves/block, BM=64 (16 node-rows per wave). K tiled in KT=64 bf16.
// LDS: xt[64 rows][64 bf16] (128B rows, chunk XOR-swizzle c^=(row&7)) and
// wt[FOUT][64 bf16] (W transposed at stage so B-frags are 16B contiguous).
// Frags: A row=lane&15, k=(lane>>4)*8+j; B col=lane&15, same k.
// C/D: col=lane&15, row=(lane>>4)*4+reg [verified m89 mapping].
// ---------------------------------------------------------------------------
template <int K1, int FOUT, bool TWO, bool X1BF, bool X2BF, bool NORM,
          bool YBF>
__global__ __launch_bounds__(256) void node_gemm_mfma(
    const void* __restrict__ X1, const void* __restrict__ X2,
    const float* __restrict__ W1, const float* __restrict__ W2,
    const float* __restrict__ B, void* __restrict__ Y, int n) {
  constexpr int KT = 64;         // K-tile in bf16 elements
  constexpr int KT2 = KT / 2;    // 32 u32 per LDS row (128B, bank-aligned)
  constexpr int NT1 = K1 / KT;
  constexpr int NT = TWO ? 2 * NT1 : NT1;
  constexpr int NFT = FOUT / 16;  // n-tiles per wave
  constexpr int BM = 64;
  __shared__ unsigned xt[BM * KT2];
  __shared__ unsigned wt[FOUT * KT2];

  const int tid = threadIdx.x;
  const int base = blockIdx.x * BM;
  const int wave = tid >> 6, lane = tid & 63;
  const int l15 = lane & 15, l4 = lane >> 4;

  f32x4 acc[NFT];
#pragma unroll
  for (int nt = 0; nt < NFT; ++nt) {
    const float b = B[nt * 16 + l15];
    acc[nt] = {b, b, b, b};
  }

  for (int t = 0; t < NT; ++t) {
    const bool second = TWO && t >= NT1;
    const int kt0 = (t % NT1) * KT;
    // ---- stage X tile (packed bf16 u32, swizzled) ----
#pragma unroll
    for (int q = 0; q < BM * KT2 / 256; ++q) {
      const int idx = tid + q * 256;
      const int r = idx >> 5, c2 = idx & 31;
      const int node = base + r;
      unsigned pk = 0;
      if (node < n) {
        if (second) {
          if (X2BF) {
            pk = reinterpret_cast<const unsigned*>(
                X2)[(size_t)node * (K1 / 2) + kt0 / 2 + c2];
          } else {
            const float2 f2 = reinterpret_cast<const float2*>(
                X2)[(size_t)node * (K1 / 2) + kt0 / 2 + c2];
            pk = f2bf(f2.x) | (f2bf(f2.y) << 16);
          }
        } else {
          if (X1BF) {
            pk = reinterpret_cast<const unsigned*>(
                X1)[(size_t)node * (K1 / 2) + kt0 / 2 + c2];
          } else {
            const float2 f2 = reinterpret_cast<const float2*>(
                X1)[(size_t)node * (K1 / 2) + kt0 / 2 + c2];
            pk = f2bf(f2.x) | (f2bf(f2.y) << 16);
          }
        }
      }
      xt[r * KT2 + (c2 ^ ((r & 7) << 2))] = pk;
    }
    // ---- stage W tile transposed: wt[f][k] = W[kt0+k][f] ----
    {
      const float* __restrict__ Ws = second ? W2 : W1;
#pragma unroll
      for (int q = 0; q < FOUT * KT2 / 256; ++q) {
        const int idx = tid + q * 256;
        const int c2 = idx / FOUT, f = idx % FOUT;
        const float w0 = Ws[(size_t)(kt0 + 2 * c2) * FOUT + f];
        const float w1 = Ws[(size_t)(kt0 + 2 * c2 + 1) * FOUT + f];
        wt[f * KT2 + (c2 ^ ((f & 7) << 2))] = f2bf(w0) | (f2bf(w1) << 16);
      }
    }
    __syncthreads();
    // ---- MFMA: 2 k-steps of K=32 ----
#pragma unroll
    for (int ks = 0; ks < 2; ++ks) {
      const int ar = wave * 16 + l15;
      const bf16x8 af = *reinterpret_cast<const bf16x8*>(
          &xt[ar * KT2 + (((ks * 4 + l4) ^ (l15 & 7)) << 2)]);
#pragma unroll
      for (int nt = 0; nt < NFT; ++nt) {
        const int f = nt * 16 + l15;
        const bf16x8 bfr = *reinterpret_cast<const bf16x8*>(
            &wt[f * KT2 + (((ks * 4 + l4) ^ (l15 & 7)) << 2)]);
        acc[nt] =
            __builtin_amdgcn_mfma_f32_16x16x32_bf16(af, bfr, acc[nt], 0, 0, 0);
      }
    }
    __syncthreads();
  }

  // ---- epilogue: lane holds D[l4*4+reg][nt*16+l15] ----
  if (NORM) {
    float ss[4] = {0.f, 0.f, 0.f, 0.f};
#pragma unroll
    for (int nt = 0; nt < NFT; ++nt)
#pragma unroll
      for (int r = 0; r < 4; ++r) ss[r] += acc[nt][r] * acc[nt][r];
#pragma unroll
    for (int r = 0; r < 4; ++r) {
#pragma unroll
      for (int off = 1; off < 16; off <<= 1) ss[r] += __shfl_xor(ss[r], off, 16);
      ss[r] = 1.0f / fmaxf(sqrtf(ss[r]), 1e-12f);
    }
#pragma unroll
    for (int nt = 0; nt < NFT; ++nt)
#pragma unroll
      for (int r = 0; r < 4; ++r) acc[nt][r] = fmaxf(acc[nt][r] * ss[r], 0.f);
  } else {
#pragma unroll
    for (int nt = 0; nt < NFT; ++nt)
#pragma unroll
      for (int r = 0; r < 4; ++r) acc[nt][r] = fmaxf(acc[nt][r], 0.f);
  }
#pragma unroll
  for (int r = 0; r < 4; ++r) {
    const int node = base + wave * 16 + l4 * 4 + r;
    if (node < n) {
#pragma unroll
      for (int nt = 0; nt < NFT; ++nt) {
        if (YBF)
          reinterpret_cast<unsigned short*>(Y)[(size_t)node * FOUT + nt * 16 +
                                               l15] =
              (unsigned short)f2bf(acc[nt][r]);
        else
          reinterpret_cast<float*>(Y)[(size_t)node * FOUT + nt * 16 + l15] =
              acc[nt][r];
      }
    }
  }
}

// ---------------------------------------------------------------------------
// bucket_fill: single-pass radix partition of edges into NBK dst-buckets.
// Capacity layout (bucket b owns bedges[b*BCAP .. b*BCAP+BCAP)) removes the
// global scan. Per 4096-edge chunk: LDS histogram -> ONE cursor atomicAdd per
// nonzero bucket -> rank via LDS atomicAdd -> clustered line-local writes.
// Packed word: src (20 bits) | dst_local (7 bits) << 20.
// ---------------------------------------------------------------------------
__global__ __launch_bounds__(256) void bucket_fill(
    const int* __restrict__ src, const int* __restrict__ dst,
    int* __restrict__ cursor, unsigned* __restrict__ bedges) {
  __shared__ int hist[NBK];
  __shared__ int bbase[NBK];
  const int tid = threadIdx.x;
  const int c0 = blockIdx.x * FCH;
  const int n4 = (min(FCH, N_EDGES - c0)) >> 2;  // int4 count in this chunk
  for (int i = tid; i < NBK; i += 256) hist[i] = 0;
  __syncthreads();
  const int4* __restrict__ s4 = reinterpret_cast<const int4*>(src + c0);
  const int4* __restrict__ d4 = reinterpret_cast<const int4*>(dst + c0);
  int4 sv[4], dv[4];
#pragma unroll
  for (int q = 0; q < 4; ++q) {
    const int i = tid + q * 256;
    if (i < n4) {
      sv[q] = s4[i];
      dv[q] = d4[i];
      atomicAdd(&hist[dv[q].x >> 7], 1);
      atomicAdd(&hist[dv[q].y >> 7], 1);
      atomicAdd(&hist[dv[q].z >> 7], 1);
      atomicAdd(&hist[dv[q].w >> 7], 1);
    }
  }
  __syncthreads();
  for (int i = tid; i < NBK; i += 256) {
    const int c = hist[i];
    bbase[i] = c ? atomicAdd(&cursor[i], c) : 0;
    hist[i] = 0;  // reuse as rank counter
  }
  __syncthreads();
#pragma unroll
  for (int q = 0; q < 4; ++q) {
    const int i = tid + q * 256;
    if (i < n4) {
#define PUT(dd, ss)                                        \
  {                                                        \
    const int b_ = (dd) >> 7;                              \
    const int r_ = bbase[b_] + atomicAdd(&hist[b_], 1);    \
    if (r_ < BCAP)                                         \
      bedges[(size_t)b_ * BCAP + r_] =                     \
          (unsigned)(ss) | ((unsigned)((dd) & 127) << 20); \
  }
      PUT(dv[q].x, sv[q].x)
      PUT(dv[q].y, sv[q].y)
      PUT(dv[q].z, sv[q].z)
      PUT(dv[q].w, sv[q].w)
#undef PUT
    }
  }
}

// ---------------------------------------------------------------------------
// bucket_sort: one block per bucket. Counting-sort the bucket's edges by
// dst_local entirely in LDS (histogram -> Hillis-Steele scan -> rank
// scatter -> coalesced write-back in place, now storing plain src ids).
// Emits ninfo[node] = beg_local | (count << 12) (both < 4096). This gives
// the gather a per-node contiguous run with zero global scan.
// ---------------------------------------------------------------------------
__global__ __launch_bounds__(256) void bucket_sort(unsigned* __restrict__ bedges,
                                                   const int* __restrict__ cnt,
                                                   int* __restrict__ ninfo) {
  __shared__ unsigned el[BCAP];
  __shared__ unsigned el2[BCAP];
  __shared__ int hist[NPB];
  __shared__ int csum[NPB];
  __shared__ int posl[NPB];
  const int b = blockIdx.x;
  const int n = min(cnt[b], BCAP);
  unsigned* __restrict__ bp = bedges + (size_t)b * BCAP;
  for (int i = threadIdx.x; i < n; i += 256) el[i] = bp[i];
  for (int i = threadIdx.x; i < NPB; i += 256) hist[i] = 0;
  __syncthreads();
  for (int i = threadIdx.x; i < n; i += 256) atomicAdd(&hist[el[i] >> 20], 1);
  __syncthreads();
  if (threadIdx.x < NPB) csum[threadIdx.x] = hist[threadIdx.x];
  __syncthreads();
  for (int off = 1; off < NPB; off <<= 1) {
    int u = 0;
    if (threadIdx.x < NPB && threadIdx.x >= off) u = csum[threadIdx.x - off];
    __syncthreads();
    if (threadIdx.x < NPB) csum[threadIdx.x] += u;
    __syncthreads();
  }
  if (threadIdx.x < NPB) {
    const int c = hist[threadIdx.x];
    const int beg = csum[threadIdx.x] - c;  // exclusive prefix
    posl[threadIdx.x] = beg;
    const int node = b * NPB + threadIdx.x;
    if (node < N_NODES) ninfo[node] = beg | (c << 12);
  }
  __syncthreads();
  for (int i = threadIdx.x; i < n; i += 256) {
    const unsigned w = el[i];
    const int p = atomicAdd(&posl[w >> 20], 1);
    el2[p] = w & 0xFFFFF;
  }
  __syncthreads();
  for (int i = threadIdx.x; i < n; i += 256) bp[i] = el2[i];
}

// ---------------------------------------------------------------------------
// gather_max_pk<LPN>: per-node segment-max over sorted bucket runs.
// LPN lanes per node, uint4 = 8 bf16/lane. No LDS, no atomics; packed
// v_pk_max_u16 folds (exact for post-ReLU bf16). Zero-init == reference's
// where(isneginf, 0) for empty segments.
// Latency-pipeline structure: max is IDEMPOTENT, so the batch index is
// clamped to `last` instead of running a scalar tail loop -- every node is
// ceil(cnt/UNR) full UNR-wide batches (duplicate folds of the last row are
// harmless and L1-hot). UNR=6 rows in flight per 16-lane group (~46 VGPR,
// launch_bounds(256,8) stays under the 64-VGPR occupancy cliff) -> ~6x the
// outstanding-miss depth of the old 4-deep+tail loop.
// ---------------------------------------------------------------------------
template <int LPN>
__global__ __launch_bounds__(256, 8) void gather_max_pk(
    const uint4* __restrict__ M4, const int* __restrict__ ninfo,
    const int* __restrict__ sedges, uint4* __restrict__ A4) {
  constexpr int GPB = 256 / LPN;
  constexpr int UNR = 6;
  const int li = threadIdx.x % LPN;
  const int g0 = blockIdx.x * GPB + threadIdx.x / LPN;
  const int stride = gridDim.x * GPB;
  for (int node = g0; node < N_NODES; node += stride) {
    const int w = ninfo[node];
    const int cnt = w >> 12;
    uint4 a = {0u, 0u, 0u, 0u};
    if (cnt) {
      const int beg = (node >> 7) * BCAP + (w & 0xFFF);
      const int last = beg + cnt - 1;
      for (int j = beg; j <= last; j += UNR) {
        int s[UNR];
#pragma unroll
        for (int q = 0; q < UNR; ++q) s[q] = sedges[min(j + q, last)];
        uint4 u[UNR];
#pragma unroll
        for (int q = 0; q < UNR; ++q) u[q] = M4[(size_t)s[q] * LPN + li];
#pragma unroll
        for (int q = 0; q < UNR; ++q) a = pkmax4(a, u[q]);
      }
    }
    A4[(size_t)node * LPN + li] = a;
  }
}

// ---------------------------------------------------------------------------
// Edge scoring, bf16 h rows (16 bf16 = 2x uint4 per row).
// ---------------------------------------------------------------------------
__global__ __launch_bounds__(256) void edge_score_bf16_kernel(
    const uint4* __restrict__ H, const int* __restrict__ src,
    const int* __restrict__ dst, const float* __restrict__ PW,
    const float* __restrict__ PB, float* __restrict__ OUT) {
  __shared__ float Wl[2 * OUT_F * N_CLS];
  __shared__ float bl[N_CLS];
  if (threadIdx.x < 2 * OUT_F * N_CLS) Wl[threadIdx.x] = PW[threadIdx.x];
  if (threadIdx.x < N_CLS) bl[threadIdx.x] = PB[threadIdx.x];
  __syncthreads();
  for (int e = blockIdx.x * 256 + threadIdx.x; e < N_EDGES;
       e += gridDim.x * 256) {
    const int s = src[e], d = dst[e];
    const uint4 s0 = H[(size_t)s * 2], s1 = H[(size_t)s * 2 + 1];
    const uint4 d0 = H[(size_t)d * 2], d1 = H[(size_t)d * 2 + 1];
    float hs[OUT_F], hd[OUT_F];
    unpack8(s0, hs); unpack8(s1, hs + 8);
    unpack8(d0, hd); unpack8(d1, hd + 8);
    float acc[N_CLS];
#pragma unroll
    for (int c = 0; c < N_CLS; ++c) acc[c] = bl[c];
#pragma unroll
    for (int k = 0; k < OUT_F; ++k) {
#pragma unroll
      for (int c = 0; c < N_CLS; ++c) {
        acc[c] = fmaf(hs[k], Wl[k * N_CLS + c], acc[c]);
        acc[c] = fmaf(hd[k], Wl[(OUT_F + k) * N_CLS + c], acc[c]);
      }
    }
    float* o = OUT + (size_t)e * N_CLS;
#pragma unroll
    for (int c = 0; c < N_CLS; ++c) o[c] = acc[c];
  }
}

extern "C" void kernel_launch(void* const* d_in, const int* in_sizes, int n_in,
                              void* d_out, int out_size, void* d_ws,
                              size_t ws_size, hipStream_t stream) {
  const float* x = (const float*)d_in[0];
  const int* src = (const int*)d_in[1];
  const int* dst = (const int*)d_in[2];
  const float* pool1_W = (const float*)d_in[3];
  const float* pool1_b = (const float*)d_in[4];
  const float* self1_W = (const float*)d_in[5];
  const float* neigh1_W = (const float*)d_in[6];
  const float* bias1 = (const float*)d_in[7];
  const float* pool2_W = (const float*)d_in[8];
  const float* pool2_b = (const float*)d_in[9];
  const float* self2_W = (const float*)d_in[10];
  const float* neigh2_W = (const float*)d_in[11];
  const float* bias2 = (const float*)d_in[12];
  const float* pred_W = (const float*)d_in[13];
  const float* pred_b = (const float*)d_in[14];
  float* out = (float*)d_out;

  // Workspace: cursor (1024) + ninfo (100352) + bedges (NBK*BCAP ~7.5MB)
  // + two 25.6MB bf16 regions. ~59.1MB total.
  int* cursor = (int*)d_ws;                      // 1024 (uses NBK=782)
  int* ninfo = cursor + 1024;                    // 100352 (uses 100000)
  unsigned* bedges = (unsigned*)(ninfo + 100352);  // 782*2400 = 1,876,800
  char* bufA = (char*)(bedges + (size_t)NBK * BCAP);  // 25.6MB
  char* bufB = bufA + 25600000;                       // 25.6MB
  void* m1 = (void*)bufA;                 // bf16 [N,128] (25.6MB)
  void* agg1 = (void*)bufB;               // bf16 [N,128]
  void* h1 = (void*)bufA;                 // bf16 [N,64] 12.8MB (m1 dead)
  void* m2 = (void*)bufB;                 // bf16 [N,64] (agg1 dead)
  void* agg2 = (void*)(bufA + 12800000);  // bf16 [N,64] (m1 upper half, dead)
  void* h2 = (void*)bufB;                 // bf16 [N,16] (m2 dead after gather2)

  // ---- edge bucketing + bucket-local counting sort ----
  hipMemsetAsync(cursor, 0, 1024 * sizeof(int), stream);
  bucket_fill<<<NCH, 256, 0, stream>>>(src, dst, cursor, bedges);
  bucket_sort<<<NBK, 256, 0, stream>>>(bedges, cursor, ninfo);

  const int ngrid = (N_NODES + 63) / 64;  // 1563

  // ---- Layer 1 ----
  node_gemm_mfma<IN_F, IN_F, false, false, false, false, true>
      <<<ngrid, 256, 0, stream>>>(x, nullptr, pool1_W, nullptr, pool1_b, m1,
                                  N_NODES);
  gather_max_pk<16><<<2048, 256, 0, stream>>>(
      (const uint4*)m1, ninfo, (const int*)bedges, (uint4*)agg1);
  node_gemm_mfma<IN_F, HID_F, true, false, true, true, true>
      <<<ngrid, 256, 0, stream>>>(x, agg1, self1_W, neigh1_W, bias1, h1,
                                  N_NODES);

  // ---- Layer 2 ----
  node_gemm_mfma<HID_F, HID_F, false, true, false, false, true>
      <<<ngrid, 256, 0, stream>>>(h1, nullptr, pool2_W, nullptr, pool2_b, m2,
                                  N_NODES);
  gather_max_pk<8><<<2048, 256, 0, stream>>>(
      (const uint4*)m2, ninfo, (const int*)bedges, (uint4*)agg2);
  node_gemm_mfma<HID_F, OUT_F, true, true, true, true, true>
      <<<ngrid, 256, 0, stream>>>(h1, agg2, self2_W, neigh2_W, bias2, h2,
                                  N_NODES);

  // ---- Edge scoring ----
  edge_score_bf16_kernel<<<4096, 256, 0, stream>>>((const uint4*)h2, src, dst,
                                                   pred_W, pred_b, out);
}